// Round 3
// baseline (515.581 us; speedup 1.0000x reference)
//
#include <hip/hip_runtime.h>
#include <hip/hip_bf16.h>
#include <math.h>

constexpr int IN_C = 1024;
constexpr int HEADS = 4;
constexpr int F1 = 256;
constexpr int OUT_C = 64;
constexpr float NEG = 0.2f;

using bf16x8 = __attribute__((ext_vector_type(8))) short;
using f32x4 = __attribute__((ext_vector_type(4))) float;

__device__ __forceinline__ float leaky(float x) { return x > 0.f ? x : NEG * x; }

__device__ __forceinline__ unsigned short bf16bits(float v) {
  __hip_bfloat16 b = __float2bfloat16(v);
  return *reinterpret_cast<unsigned short*>(&b);
}
__device__ __forceinline__ float bf2f(unsigned short u) {
  union { unsigned u; float f; } c; c.u = (unsigned)u << 16; return c.f;
}

#define GLD_LDS16(g, l)                                                        \
  __builtin_amdgcn_global_load_lds(                                            \
      (const __attribute__((address_space(1))) void*)(g),                      \
      (__attribute__((address_space(3))) void*)(l), 16, 0, 0)

// ---------------- fused prep: cvt W1 -> bf16, cvt W2 -> bf16, degree count ----------------
// block-range dispatch: [0,1024) = W1, [1024,1088) = W2, rest = degree.
constexpr int NB_W1 = (F1 * IN_C) / 256;    // 1024 (exact)
constexpr int NB_W2 = (OUT_C * F1) / 256;   // 64 (exact)

__global__ __launch_bounds__(256) void prep_kernel(const float* __restrict__ W1,
                                                   unsigned short* __restrict__ W1b,
                                                   const float* __restrict__ W2,
                                                   unsigned short* __restrict__ W2b,
                                                   const int* __restrict__ ei, int E, int N,
                                                   int* __restrict__ deg) {
  int b = blockIdx.x;
  if (b < NB_W1) {
    int i = b * 256 + threadIdx.x;
    W1b[i] = bf16bits(W1[i]);
  } else if (b < NB_W1 + NB_W2) {
    int i = (b - NB_W1) * 256 + threadIdx.x;
    W2b[i] = bf16bits(W2[i]);
  } else {
    int e = (b - NB_W1 - NB_W2) * 256 + threadIdx.x;
    if (e < E + N) {
      int dst = (e < E) ? ei[E + e] : (e - E);
      atomicAdd(&deg[dst], 1);
    }
  }
}

// ------- GEMM1: Hb[M,256] = X*W1^T (bf16 MFMA) + fused alpha dot-products ---------
// 64-row x 256-col blocks, 256 threads (4 waves, wave = 64x64 col-group/head).
// 782 blocks -> 3.05/CU balanced; LDS 41KB -> 3 blocks/CU resident so cross-block
// overlap hides the per-K-tile vmcnt(0)+barrier drain (round-2's 128-row tile gave
// only 1.53 blocks/CU -> 2x makespan quantization, MfmaUtil 8%).
// X prefetched one K-tile ahead into registers (global loads only; ds_write stays
// behind the barrier -> no hazard, identical accumulation order).
// Scatter fused as trailing blocks (independent work co-scheduled).
constexpr int LDTA = 72;

__global__ __launch_bounds__(256, 3) void gemm1_mfma(const float* __restrict__ X,
                                                     const unsigned short* __restrict__ Wb,
                                                     unsigned short* __restrict__ Hb,
                                                     const float* __restrict__ a_src,
                                                     const float* __restrict__ a_dst,
                                                     float* __restrict__ as_out,
                                                     float* __restrict__ ad_out, int M, int MB,
                                                     const int* __restrict__ ei, int E, int N,
                                                     const int* __restrict__ row_ptr,
                                                     int* __restrict__ fill,
                                                     int* __restrict__ col) {
  __shared__ unsigned short As[64 * LDTA];
  __shared__ unsigned short Bs[256 * 64];
  const int tid = threadIdx.x;

  if (blockIdx.x >= MB) {
    // ---- fused scatter (CSR column fill) ----
    int e = (blockIdx.x - MB) * 256 + tid;
    int ET = E + N;
    if (e < ET) {
      int src, dst;
      if (e < E) { src = ei[e]; dst = ei[E + e]; }
      else       { src = e - E; dst = e - E; }
      int pos = row_ptr[dst] + atomicAdd(&fill[dst], 1);
      col[pos] = src;
    }
    return;
  }

  const int wave = tid >> 6;   // col-group / head: 0..3 (64 cols each)
  const int lane = tid & 63;
  const int m15 = lane & 15;
  const int q = lane >> 4;
  const int bm = blockIdx.x * 64;

  f32x4 acc[4][4];
#pragma unroll
  for (int i = 0; i < 4; ++i)
#pragma unroll
    for (int j = 0; j < 4; ++j) acc[i][j] = (f32x4){0.f, 0.f, 0.f, 0.f};

  const int ar = tid >> 2;           // 0..63: A row within tile
  const int acg = (tid & 3) * 16;    // 16-col chunk within K-tile
  const int agr = (bm + ar < M) ? (bm + ar) : (M - 1);
  const float* aptr = X + (size_t)agr * IN_C + acg;

  // prefetch first K-tile of X
  float4 a0 = *(const float4*)(aptr + 0);
  float4 a1 = *(const float4*)(aptr + 4);
  float4 a2 = *(const float4*)(aptr + 8);
  float4 a3 = *(const float4*)(aptr + 12);

  for (int kt = 0; kt < IN_C; kt += 64) {
    // B staging (L2-resident after first touch): 2048 16B-slots / 256 threads = 8
#pragma unroll
    for (int p = 0; p < 8; ++p) {
      int s = p * 256 + tid;
      int r = s >> 3;
      int cb = s & 7;
      const unsigned short* g = Wb + (size_t)r * IN_C + kt + ((cb ^ (r & 7)) << 3);
      GLD_LDS16(g, &Bs[(p * 256 + wave * 64) * 8]);
    }
    union { uint4 u4[2]; __hip_bfloat162 h[8]; } pk;
    pk.h[0] = __float22bfloat162_rn(make_float2(a0.x, a0.y));
    pk.h[1] = __float22bfloat162_rn(make_float2(a0.z, a0.w));
    pk.h[2] = __float22bfloat162_rn(make_float2(a1.x, a1.y));
    pk.h[3] = __float22bfloat162_rn(make_float2(a1.z, a1.w));
    pk.h[4] = __float22bfloat162_rn(make_float2(a2.x, a2.y));
    pk.h[5] = __float22bfloat162_rn(make_float2(a2.z, a2.w));
    pk.h[6] = __float22bfloat162_rn(make_float2(a3.x, a3.y));
    pk.h[7] = __float22bfloat162_rn(make_float2(a3.z, a3.w));
    *(uint4*)&As[ar * LDTA + acg] = pk.u4[0];
    *(uint4*)&As[ar * LDTA + acg + 8] = pk.u4[1];
    // prefetch next K-tile of X (global only; lands during this tile's MFMA phase)
    if (kt + 64 < IN_C) {
      a0 = *(const float4*)(aptr + kt + 64 + 0);
      a1 = *(const float4*)(aptr + kt + 64 + 4);
      a2 = *(const float4*)(aptr + kt + 64 + 8);
      a3 = *(const float4*)(aptr + kt + 64 + 12);
    }
    __syncthreads();

#pragma unroll
    for (int k0 = 0; k0 < 64; k0 += 32) {
      bf16x8 af[4], bfr[4];
#pragma unroll
      for (int i = 0; i < 4; ++i)
        af[i] = *(const bf16x8*)&As[(i * 16 + m15) * LDTA + k0 + q * 8];
#pragma unroll
      for (int j = 0; j < 4; ++j) {
        int rb = wave * 64 + j * 16 + m15;
        int cbp = ((k0 >> 3) + q) ^ (rb & 7);
        bfr[j] = *(const bf16x8*)&Bs[rb * 64 + cbp * 8];
      }
#pragma unroll
      for (int i = 0; i < 4; ++i)
#pragma unroll
        for (int j = 0; j < 4; ++j)
          acc[i][j] = __builtin_amdgcn_mfma_f32_16x16x32_bf16(af[i], bfr[j], acc[i][j], 0, 0, 0);
    }
    __syncthreads();
  }
  float asf[4], adf[4];
#pragma unroll
  for (int j = 0; j < 4; ++j) {
    asf[j] = a_src[wave * 64 + j * 16 + m15];
    adf[j] = a_dst[wave * 64 + j * 16 + m15];
  }
#pragma unroll
  for (int i = 0; i < 4; ++i) {
#pragma unroll
    for (int r = 0; r < 4; ++r) {
      int row = bm + i * 16 + q * 4 + r;
      if (row < M) {
#pragma unroll
        for (int j = 0; j < 4; ++j)
          Hb[(size_t)row * F1 + wave * 64 + j * 16 + m15] = bf16bits(acc[i][j][r]);
      }
      float s = acc[i][0][r] * asf[0] + acc[i][1][r] * asf[1] +
                acc[i][2][r] * asf[2] + acc[i][3][r] * asf[3];
      float d = acc[i][0][r] * adf[0] + acc[i][1][r] * adf[1] +
                acc[i][2][r] * adf[2] + acc[i][3][r] * adf[3];
#pragma unroll
      for (int o = 1; o < 16; o <<= 1) {
        s += __shfl_xor(s, o, 64);
        d += __shfl_xor(d, o, 64);
      }
      if (m15 == 0 && row < M) {
        as_out[row * HEADS + wave] = s;
        ad_out[row * HEADS + wave] = d;
      }
    }
  }
}

// ------- GEMM2: H2[M,64] = Y(bf16)*W2^T (bf16 MFMA) + fused alpha -----------------
__global__ __launch_bounds__(256, 4) void gemm2_mfma(const unsigned short* __restrict__ Y,
                                                     const unsigned short* __restrict__ W2b,
                                                     float* __restrict__ H2,
                                                     const float* __restrict__ a_src,
                                                     const float* __restrict__ a_dst,
                                                     float* __restrict__ as_out,
                                                     float* __restrict__ ad_out, int M) {
  __shared__ unsigned short As[64 * 64];
  __shared__ unsigned short Bs[64 * 64];
  const int tid = threadIdx.x;
  const int wave = tid >> 6;
  const int lane = tid & 63;
  const int m15 = lane & 15;
  const int q = lane >> 4;
  const int bm = blockIdx.x * 64;

  f32x4 acc[4];
#pragma unroll
  for (int j = 0; j < 4; ++j) acc[j] = (f32x4){0.f, 0.f, 0.f, 0.f};

  for (int kt = 0; kt < F1; kt += 64) {
#pragma unroll
    for (int p = 0; p < 2; ++p) {
      int s = p * 256 + tid;
      int r = s >> 3;
      int cb = s & 7;
      int colo = (cb ^ (r & 7)) << 3;
      int gr = (bm + r < M) ? (bm + r) : (M - 1);
      GLD_LDS16(Y + (size_t)gr * F1 + kt + colo, &As[(p * 256 + wave * 64) * 8]);
      GLD_LDS16(W2b + (size_t)r * F1 + kt + colo, &Bs[(p * 256 + wave * 64) * 8]);
    }
    __syncthreads();
#pragma unroll
    for (int k0 = 0; k0 < 64; k0 += 32) {
      int ra = wave * 16 + m15;
      bf16x8 af = *(const bf16x8*)&As[ra * 64 + ((((k0 >> 3) + q) ^ (ra & 7)) << 3)];
      bf16x8 bfr[4];
#pragma unroll
      for (int j = 0; j < 4; ++j) {
        int rb = j * 16 + m15;
        bfr[j] = *(const bf16x8*)&Bs[rb * 64 + ((((k0 >> 3) + q) ^ (rb & 7)) << 3)];
      }
#pragma unroll
      for (int j = 0; j < 4; ++j)
        acc[j] = __builtin_amdgcn_mfma_f32_16x16x32_bf16(af, bfr[j], acc[j], 0, 0, 0);
    }
    __syncthreads();
  }
  float asf[4], adf[4];
#pragma unroll
  for (int j = 0; j < 4; ++j) {
    asf[j] = a_src[j * 16 + m15];
    adf[j] = a_dst[j * 16 + m15];
  }
#pragma unroll
  for (int r = 0; r < 4; ++r) {
    int row = bm + wave * 16 + q * 4 + r;
    if (row < M) {
#pragma unroll
      for (int j = 0; j < 4; ++j) H2[(size_t)row * OUT_C + j * 16 + m15] = acc[j][r];
    }
    float s = acc[0][r] * asf[0] + acc[1][r] * asf[1] + acc[2][r] * asf[2] + acc[3][r] * asf[3];
    float d = acc[0][r] * adf[0] + acc[1][r] * adf[1] + acc[2][r] * adf[2] + acc[3][r] * adf[3];
#pragma unroll
    for (int o = 1; o < 16; o <<= 1) {
      s += __shfl_xor(s, o, 64);
      d += __shfl_xor(d, o, 64);
    }
    if (m15 == 0 && row < M) {
      as_out[row] = s;
      ad_out[row] = d;
    }
  }
}

// ---------------- CSR build ----------------
__global__ __launch_bounds__(256) void scan_block_sums(const int* __restrict__ deg,
                                                       int* __restrict__ part, int n) {
  __shared__ int sm[256];
  int t = threadIdx.x;
  int i = blockIdx.x * 256 + t;
  sm[t] = (i < n) ? deg[i] : 0;
  __syncthreads();
  for (int off = 128; off > 0; off >>= 1) {
    if (t < off) sm[t] += sm[t + off];
    __syncthreads();
  }
  if (t == 0) part[blockIdx.x] = sm[0];
}

// final scan: each block computes its own exclusive base from raw block sums
// (P <= 256 partials -> one wave-butterfly + LDS combine)
__global__ __launch_bounds__(256) void scan_final2(const int* __restrict__ deg,
                                                   const int* __restrict__ part,
                                                   int* __restrict__ row_ptr, int n) {
  __shared__ int sm[256];
  __shared__ int wsum[4];
  int t = threadIdx.x;
  int i = blockIdx.x * 256 + t;
  sm[t] = (i < n) ? deg[i] : 0;
  // exclusive base = sum of part[0..blockIdx.x-1]
  int pv = (t < blockIdx.x) ? part[t] : 0;
#pragma unroll
  for (int o = 1; o < 64; o <<= 1) pv += __shfl_xor(pv, o, 64);
  if ((t & 63) == 0) wsum[t >> 6] = pv;
  __syncthreads();
  for (int off = 1; off < 256; off <<= 1) {
    int u = (t >= off) ? sm[t - off] : 0;
    __syncthreads();
    sm[t] += u;
    __syncthreads();
  }
  int base = wsum[0] + wsum[1] + wsum[2] + wsum[3];
  if (i < n) row_ptr[i + 1] = base + sm[t];
  if (i == 0) row_ptr[0] = 0;
}

// ------- layer-1 aggregate: wave/dst, FOUR edges in flight per 32-lane half --------
// lane&31 = channel-group (8 ch, uint4), lane>>5 = edge parity; head = (lane&31)>>3.
__global__ __launch_bounds__(256) void agg1_kernel(const unsigned short* __restrict__ hb,
                                                   const float* __restrict__ as,
                                                   const float* __restrict__ ad,
                                                   const int* __restrict__ row_ptr,
                                                   const int* __restrict__ col,
                                                   const float* __restrict__ bias,
                                                   unsigned short* __restrict__ yb, int N) {
  int dst = (blockIdx.x * blockDim.x + threadIdx.x) >> 6;
  int lane = threadIdx.x & 63;
  if (dst >= N) return;
  const int s0 = row_ptr[dst], s1 = row_ptr[dst + 1];
  const int par = lane >> 5;
  const int cg = lane & 31;
  const int hh = cg >> 3;
  const float adl = ad[dst * 4 + hh];
  float acc[8];
#pragma unroll
  for (int k = 0; k < 8; ++k) acc[k] = 0.f;
  float den = 0.f;

  int i = s0 + par;
  for (; i + 6 < s1; i += 8) {  // 4 edges per parity per iter -> 8 rows in flight
    int sA = col[i], sB = col[i + 2], sC = col[i + 4], sD = col[i + 6];
    float wA = __expf(leaky(as[sA * 4 + hh] + adl));
    float wB = __expf(leaky(as[sB * 4 + hh] + adl));
    float wC = __expf(leaky(as[sC * 4 + hh] + adl));
    float wD = __expf(leaky(as[sD * 4 + hh] + adl));
    uint4 hA = *(const uint4*)(hb + (size_t)sA * F1 + cg * 8);
    uint4 hB = *(const uint4*)(hb + (size_t)sB * F1 + cg * 8);
    uint4 hC = *(const uint4*)(hb + (size_t)sC * F1 + cg * 8);
    uint4 hD = *(const uint4*)(hb + (size_t)sD * F1 + cg * 8);
    den += (wA + wB) + (wC + wD);
    const unsigned short* pa = (const unsigned short*)&hA;
    const unsigned short* pb = (const unsigned short*)&hB;
    const unsigned short* pc = (const unsigned short*)&hC;
    const unsigned short* pd = (const unsigned short*)&hD;
#pragma unroll
    for (int k = 0; k < 8; ++k) {
      acc[k] = fmaf(wA, bf2f(pa[k]), acc[k]);
      acc[k] = fmaf(wB, bf2f(pb[k]), acc[k]);
      acc[k] = fmaf(wC, bf2f(pc[k]), acc[k]);
      acc[k] = fmaf(wD, bf2f(pd[k]), acc[k]);
    }
  }
  for (; i + 2 < s1; i += 4) {  // 2 edges per parity
    int sA = col[i], sB = col[i + 2];
    float wA = __expf(leaky(as[sA * 4 + hh] + adl));
    float wB = __expf(leaky(as[sB * 4 + hh] + adl));
    uint4 hA = *(const uint4*)(hb + (size_t)sA * F1 + cg * 8);
    uint4 hB = *(const uint4*)(hb + (size_t)sB * F1 + cg * 8);
    den += wA + wB;
    const unsigned short* pa = (const unsigned short*)&hA;
    const unsigned short* pb = (const unsigned short*)&hB;
#pragma unroll
    for (int k = 0; k < 8; ++k) {
      acc[k] = fmaf(wA, bf2f(pa[k]), acc[k]);
      acc[k] = fmaf(wB, bf2f(pb[k]), acc[k]);
    }
  }
  for (; i < s1; i += 2) {
    int s = col[i];
    float w = __expf(leaky(as[s * 4 + hh] + adl));
    uint4 hv = *(const uint4*)(hb + (size_t)s * F1 + cg * 8);
    den += w;
    const unsigned short* p = (const unsigned short*)&hv;
#pragma unroll
    for (int k = 0; k < 8; ++k) acc[k] = fmaf(w, bf2f(p[k]), acc[k]);
  }
  // combine the two parities
  den += __shfl_xor(den, 32, 64);
#pragma unroll
  for (int k = 0; k < 8; ++k) acc[k] += __shfl_xor(acc[k], 32, 64);

  if (par == 0) {
    const float iv = 1.f / den;
    float4 b0 = *(const float4*)(bias + cg * 8);
    float4 b1 = *(const float4*)(bias + cg * 8 + 4);
    float bv[8] = {b0.x, b0.y, b0.z, b0.w, b1.x, b1.y, b1.z, b1.w};
    ushort4 o[2];
    unsigned short* po = (unsigned short*)o;
#pragma unroll
    for (int k = 0; k < 8; ++k) {
      float v = acc[k] * iv + bv[k];
      v = v > 0.f ? v : (__expf(v) - 1.f);
      po[k] = bf16bits(v);
    }
    *(uint4*)(yb + (size_t)dst * F1 + cg * 8) = *(uint4*)o;
  }
}

// ------- layer-2 aggregate: wave/dst, FOUR edges in flight per half ----------------
__global__ __launch_bounds__(256) void agg2_kernel(const float* __restrict__ h,
                                                   const float* __restrict__ as,
                                                   const float* __restrict__ ad,
                                                   const int* __restrict__ row_ptr,
                                                   const int* __restrict__ col,
                                                   const float* __restrict__ bias,
                                                   float* __restrict__ out, int N) {
  int dst = (blockIdx.x * blockDim.x + threadIdx.x) >> 6;
  int lane = threadIdx.x & 63;
  if (dst >= N) return;
  const int s0 = row_ptr[dst], s1 = row_ptr[dst + 1];
  const int par = lane >> 5;
  const int cg = lane & 31;
  const float adl = ad[dst];
  float a0 = 0.f, a1 = 0.f, den = 0.f;

  int i = s0 + par;
  for (; i + 6 < s1; i += 8) {
    int sA = col[i], sB = col[i + 2], sC = col[i + 4], sD = col[i + 6];
    float wA = __expf(leaky(as[sA] + adl));
    float wB = __expf(leaky(as[sB] + adl));
    float wC = __expf(leaky(as[sC] + adl));
    float wD = __expf(leaky(as[sD] + adl));
    float2 hA = *(const float2*)(h + (size_t)sA * OUT_C + cg * 2);
    float2 hB = *(const float2*)(h + (size_t)sB * OUT_C + cg * 2);
    float2 hC = *(const float2*)(h + (size_t)sC * OUT_C + cg * 2);
    float2 hD = *(const float2*)(h + (size_t)sD * OUT_C + cg * 2);
    den += (wA + wB) + (wC + wD);
    a0 = fmaf(wA, hA.x, a0); a1 = fmaf(wA, hA.y, a1);
    a0 = fmaf(wB, hB.x, a0); a1 = fmaf(wB, hB.y, a1);
    a0 = fmaf(wC, hC.x, a0); a1 = fmaf(wC, hC.y, a1);
    a0 = fmaf(wD, hD.x, a0); a1 = fmaf(wD, hD.y, a1);
  }
  for (; i + 2 < s1; i += 4) {
    int sA = col[i], sB = col[i + 2];
    float wA = __expf(leaky(as[sA] + adl));
    float wB = __expf(leaky(as[sB] + adl));
    float2 hA = *(const float2*)(h + (size_t)sA * OUT_C + cg * 2);
    float2 hB = *(const float2*)(h + (size_t)sB * OUT_C + cg * 2);
    den += wA + wB;
    a0 = fmaf(wA, hA.x, a0); a1 = fmaf(wA, hA.y, a1);
    a0 = fmaf(wB, hB.x, a0); a1 = fmaf(wB, hB.y, a1);
  }
  for (; i < s1; i += 2) {
    int s = col[i];
    float w = __expf(leaky(as[s] + adl));
    float2 hv = *(const float2*)(h + (size_t)s * OUT_C + cg * 2);
    den += w;
    a0 = fmaf(w, hv.x, a0); a1 = fmaf(w, hv.y, a1);
  }
  den += __shfl_xor(den, 32, 64);
  a0 += __shfl_xor(a0, 32, 64);
  a1 += __shfl_xor(a1, 32, 64);
  if (par == 0) {
    const float iv = 1.f / den;
    float2 bv = *(const float2*)(bias + cg * 2);
    float2 o = make_float2(a0 * iv + bv.x, a1 * iv + bv.y);
    *(float2*)(out + (size_t)dst * OUT_C + cg * 2) = o;
  }
}

extern "C" void kernel_launch(void* const* d_in, const int* in_sizes, int n_in,
                              void* d_out, int out_size, void* d_ws, size_t ws_size,
                              hipStream_t stream) {
  const float* x      = (const float*)d_in[0];
  const int*   ei     = (const int*)d_in[1];
  const float* W1     = (const float*)d_in[2];
  const float* a_src1 = (const float*)d_in[3];
  const float* a_dst1 = (const float*)d_in[4];
  const float* b1     = (const float*)d_in[5];
  const float* W2     = (const float*)d_in[6];
  const float* a_src2 = (const float*)d_in[7];
  const float* a_dst2 = (const float*)d_in[8];
  const float* b2     = (const float*)d_in[9];
  float* out = (float*)d_out;

  const int N = in_sizes[0] / IN_C;
  const int E = in_sizes[1] / 2;
  const int ET = E + N;

  char* ws = (char*)d_ws;
  size_t off = 0;
  auto alloc = [&](size_t bytes) -> void* {
    void* p = ws + off;
    off = (off + bytes + 255) & ~(size_t)255;
    return p;
  };
  unsigned short* h1b = (unsigned short*)alloc((size_t)N * F1 * 2);
  unsigned short* y1b = (unsigned short*)alloc((size_t)N * F1 * 2);
  float* h2      = (float*)alloc((size_t)N * OUT_C * 4);
  float* as1     = (float*)alloc((size_t)N * HEADS * 4);
  float* ad1     = (float*)alloc((size_t)N * HEADS * 4);
  float* as2     = (float*)alloc((size_t)N * 4);
  float* ad2     = (float*)alloc((size_t)N * 4);
  int*   deg     = (int*)alloc((size_t)N * 2 * 4);  // deg + fill, contiguous -> one memset
  int*   fill    = deg + N;
  int*   row_ptr = (int*)alloc((size_t)(N + 1) * 4);
  int*   col     = (int*)alloc((size_t)ET * 4);
  int*   part    = (int*)alloc(1024 * 4);
  unsigned short* W1b = (unsigned short*)alloc((size_t)F1 * IN_C * 2);
  unsigned short* W2b = (unsigned short*)alloc((size_t)OUT_C * F1 * 2);
  (void)off; (void)ws_size; (void)n_in; (void)out_size;

  hipMemsetAsync(deg, 0, (size_t)N * 2 * 4, stream);

  const int NBD = (ET + 255) / 256;
  const int P = (N + 255) / 256;  // scan_final2 requires P <= 256 (N <= 65536): holds for N=50000

  prep_kernel<<<NB_W1 + NB_W2 + NBD, 256, 0, stream>>>(W1, W1b, W2, W2b, ei, E, N, deg);
  scan_block_sums<<<P, 256, 0, stream>>>(deg, part, N);
  scan_final2<<<P, 256, 0, stream>>>(deg, part, row_ptr, N);

  const int NB4 = (N + 3) / 4;
  const int MB = (N + 63) / 64;      // 782 gemm blocks -> 3.05/CU
  const int SB = (ET + 255) / 256;   // scatter trailing blocks

  // ---- layer 1 (gemm + fused scatter: independent work co-scheduled) ----
  gemm1_mfma<<<MB + SB, 256, 0, stream>>>(x, W1b, h1b, a_src1, a_dst1, as1, ad1, N, MB,
                                          ei, E, N, row_ptr, fill, col);
  agg1_kernel<<<NB4, 256, 0, stream>>>(h1b, as1, ad1, row_ptr, col, b1, y1b, N);

  // ---- layer 2 ----
  gemm2_mfma<<<(N + 63) / 64, 256, 0, stream>>>(y1b, W2b, h2, a_src2, a_dst2, as2, ad2, N);
  agg2_kernel<<<NB4, 256, 0, stream>>>(h2, as2, ad2, row_ptr, col, b2, out, N);
}

// Round 5
// 504.326 us; speedup vs baseline: 1.0223x; 1.0223x over previous
//
#include <hip/hip_runtime.h>
#include <hip/hip_bf16.h>
#include <math.h>

constexpr int IN_C = 1024;
constexpr int HEADS = 4;
constexpr int F1 = 256;
constexpr int OUT_C = 64;
constexpr float NEG = 0.2f;

using bf16x8 = __attribute__((ext_vector_type(8))) short;
using f32x4 = __attribute__((ext_vector_type(4))) float;

__device__ __forceinline__ float leaky(float x) { return x > 0.f ? x : NEG * x; }

__device__ __forceinline__ unsigned short bf16bits(float v) {
  __hip_bfloat16 b = __float2bfloat16(v);
  return *reinterpret_cast<unsigned short*>(&b);
}
__device__ __forceinline__ float bf2f(unsigned short u) {
  union { unsigned u; float f; } c; c.u = (unsigned)u << 16; return c.f;
}

#define GLD_LDS16(g, l)                                                        \
  __builtin_amdgcn_global_load_lds(                                            \
      (const __attribute__((address_space(1))) void*)(g),                      \
      (__attribute__((address_space(3))) void*)(l), 16, 0, 0)

// ---------------- fused prep: cvt W1 -> bf16, cvt W2 -> bf16, degree count ----------------
// block-range dispatch: [0,1024) = W1, [1024,1088) = W2, rest = degree.
constexpr int NB_W1 = (F1 * IN_C) / 256;    // 1024 (exact)
constexpr int NB_W2 = (OUT_C * F1) / 256;   // 64 (exact)

__global__ __launch_bounds__(256) void prep_kernel(const float* __restrict__ W1,
                                                   unsigned short* __restrict__ W1b,
                                                   const float* __restrict__ W2,
                                                   unsigned short* __restrict__ W2b,
                                                   const int* __restrict__ ei, int E, int N,
                                                   int* __restrict__ deg) {
  int b = blockIdx.x;
  if (b < NB_W1) {
    int i = b * 256 + threadIdx.x;
    W1b[i] = bf16bits(W1[i]);
  } else if (b < NB_W1 + NB_W2) {
    int i = (b - NB_W1) * 256 + threadIdx.x;
    W2b[i] = bf16bits(W2[i]);
  } else {
    int e = (b - NB_W1 - NB_W2) * 256 + threadIdx.x;
    if (e < E + N) {
      int dst = (e < E) ? ei[E + e] : (e - E);
      atomicAdd(&deg[dst], 1);
    }
  }
}

// ------- GEMM1: Hb[M,256] = X*W1^T (bf16 MFMA) + fused alpha dot-products ---------
// m97-shaped K-loop: BOTH operands staged via global_load_lds (width 16).
// A staged as RAW FP32 (GLD of 4 floats), converted to bf16 at fragment-read time
// (same _rn rounding as before -> bit-identical). Kills the VGPR round-trip /
// pack phase / exposed A HBM latency of rounds 0-3.
// 128-row x 128-col blocks, 256 threads (4 waves = 2 row-groups x 2 col-groups).
// Grid 782 (~3/CU), LDS 48KB -> 3 blocks/CU resident: capacity == grid, unlike
// round-2 (capacity 3, grid 1.5/CU) and round-3 (grid 3, 2x B-restage traffic).
// B-restage total stays at round-2's 196MB (row-chunks=391).
// A: 16-chunk (16B each) XOR swizzle; B: 8-chunk swizzle (proven).
// Scatter fused as trailing blocks (independent work co-scheduled).
__global__ __launch_bounds__(256, 3) void gemm1_mfma(const float* __restrict__ X,
                                                     const unsigned short* __restrict__ Wb,
                                                     unsigned short* __restrict__ Hb,
                                                     const float* __restrict__ a_src,
                                                     const float* __restrict__ a_dst,
                                                     float* __restrict__ as_out,
                                                     float* __restrict__ ad_out, int M, int MB2,
                                                     const int* __restrict__ ei, int E, int N,
                                                     const int* __restrict__ row_ptr,
                                                     int* __restrict__ fill,
                                                     int* __restrict__ col) {
  __shared__ float As4[128 * 64];           // fp32 A-tile: 128 rows x 64 K (32 KB)
  __shared__ unsigned short Bs[128 * 64];   // bf16 B-tile: 128 cols x 64 K (16 KB)
  const int tid = threadIdx.x;

  if (blockIdx.x >= MB2) {
    // ---- fused scatter (CSR column fill) ----
    int e = (blockIdx.x - MB2) * 256 + tid;
    int ET = E + N;
    if (e < ET) {
      int src, dst;
      if (e < E) { src = ei[e]; dst = ei[E + e]; }
      else       { src = e - E; dst = e - E; }
      int pos = row_ptr[dst] + atomicAdd(&fill[dst], 1);
      col[pos] = src;
    }
    return;
  }

  const int rc = blockIdx.x >> 1;    // row-chunk (adjacent blocks share A rows -> L2 reuse)
  const int colg = blockIdx.x & 1;   // column half: cols [colg*128, colg*128+128)
  const int wave = tid >> 6;
  const int rg = wave >> 1;          // row-group 0..1 (64 rows each)
  const int cg = wave & 1;           // col-group 0..1 (64 cols each)
  const int lane = tid & 63;
  const int m15 = lane & 15;
  const int q = lane >> 4;
  const int bm = rc * 128;

  f32x4 acc[4][4];
#pragma unroll
  for (int i = 0; i < 4; ++i)
#pragma unroll
    for (int j = 0; j < 4; ++j) acc[i][j] = (f32x4){0.f, 0.f, 0.f, 0.f};

  for (int kt = 0; kt < IN_C; kt += 64) {
    // A staging: 2048 16B-slots (128 rows x 16 chunks of 4 floats), 8 per thread.
    // LDS slot (r, cb) holds global chunk (cb ^ (r&15)); linear dest, pre-swizzled src.
#pragma unroll
    for (int p = 0; p < 8; ++p) {
      int s = p * 256 + tid;
      int r = s >> 4;
      int cb = s & 15;
      int gr = (bm + r < M) ? (bm + r) : (M - 1);
      const float* g = X + (size_t)gr * IN_C + kt + ((cb ^ (r & 15)) << 2);
      GLD_LDS16(g, &As4[s * 4]);
    }
    // B staging: 1024 16B-slots (128 cols x 8 chunks of 8 bf16), 4 per thread.
#pragma unroll
    for (int p = 0; p < 4; ++p) {
      int t = p * 256 + tid;
      int rB = t >> 3;
      int cbB = t & 7;
      const unsigned short* g = Wb + (size_t)(colg * 128 + rB) * IN_C + kt + ((cbB ^ (rB & 7)) << 3);
      GLD_LDS16(g, &Bs[t * 8]);
    }
    __syncthreads();

#pragma unroll
    for (int k0 = 0; k0 < 64; k0 += 32) {
      bf16x8 af[4], bfr[4];
#pragma unroll
      for (int i = 0; i < 4; ++i) {
        int ra = rg * 64 + i * 16 + m15;
        int c0 = (k0 >> 2) + q * 2;   // first 4-float chunk of this lane's 8 K-elems
        float4 f0 = *(const float4*)&As4[ra * 64 + ((c0 ^ (ra & 15)) << 2)];
        float4 f1 = *(const float4*)&As4[ra * 64 + (((c0 + 1) ^ (ra & 15)) << 2)];
        union { bf16x8 v; __hip_bfloat162 h[4]; } pk;
        pk.h[0] = __float22bfloat162_rn(make_float2(f0.x, f0.y));
        pk.h[1] = __float22bfloat162_rn(make_float2(f0.z, f0.w));
        pk.h[2] = __float22bfloat162_rn(make_float2(f1.x, f1.y));
        pk.h[3] = __float22bfloat162_rn(make_float2(f1.z, f1.w));
        af[i] = pk.v;
      }
#pragma unroll
      for (int j = 0; j < 4; ++j) {
        int rb = cg * 64 + j * 16 + m15;
        int cbp = ((k0 >> 3) + q) ^ (rb & 7);
        bfr[j] = *(const bf16x8*)&Bs[rb * 64 + cbp * 8];
      }
#pragma unroll
      for (int i = 0; i < 4; ++i)
#pragma unroll
        for (int j = 0; j < 4; ++j)
          acc[i][j] = __builtin_amdgcn_mfma_f32_16x16x32_bf16(af[i], bfr[j], acc[i][j], 0, 0, 0);
    }
    __syncthreads();
  }

  const int cbase = colg * 128 + cg * 64;   // this wave's 64-col slice
  const int head = colg * 2 + cg;
  float asf[4], adf[4];
#pragma unroll
  for (int j = 0; j < 4; ++j) {
    asf[j] = a_src[cbase + j * 16 + m15];
    adf[j] = a_dst[cbase + j * 16 + m15];
  }
#pragma unroll
  for (int i = 0; i < 4; ++i) {
#pragma unroll
    for (int r = 0; r < 4; ++r) {
      int row = bm + rg * 64 + i * 16 + q * 4 + r;
      if (row < M) {
#pragma unroll
        for (int j = 0; j < 4; ++j)
          Hb[(size_t)row * F1 + cbase + j * 16 + m15] = bf16bits(acc[i][j][r]);
      }
      float s = acc[i][0][r] * asf[0] + acc[i][1][r] * asf[1] +
                acc[i][2][r] * asf[2] + acc[i][3][r] * asf[3];
      float d = acc[i][0][r] * adf[0] + acc[i][1][r] * adf[1] +
                acc[i][2][r] * adf[2] + acc[i][3][r] * adf[3];
#pragma unroll
      for (int o = 1; o < 16; o <<= 1) {
        s += __shfl_xor(s, o, 64);
        d += __shfl_xor(d, o, 64);
      }
      if (m15 == 0 && row < M) {
        as_out[row * HEADS + head] = s;
        ad_out[row * HEADS + head] = d;
      }
    }
  }
}

// ------- GEMM2: H2[M,64] = Y(bf16)*W2^T (bf16 MFMA) + fused alpha -----------------
__global__ __launch_bounds__(256, 4) void gemm2_mfma(const unsigned short* __restrict__ Y,
                                                     const unsigned short* __restrict__ W2b,
                                                     float* __restrict__ H2,
                                                     const float* __restrict__ a_src,
                                                     const float* __restrict__ a_dst,
                                                     float* __restrict__ as_out,
                                                     float* __restrict__ ad_out, int M) {
  __shared__ unsigned short As[64 * 64];
  __shared__ unsigned short Bs[64 * 64];
  const int tid = threadIdx.x;
  const int wave = tid >> 6;
  const int lane = tid & 63;
  const int m15 = lane & 15;
  const int q = lane >> 4;
  const int bm = blockIdx.x * 64;

  f32x4 acc[4];
#pragma unroll
  for (int j = 0; j < 4; ++j) acc[j] = (f32x4){0.f, 0.f, 0.f, 0.f};

  for (int kt = 0; kt < F1; kt += 64) {
#pragma unroll
    for (int p = 0; p < 2; ++p) {
      int s = p * 256 + tid;
      int r = s >> 3;
      int cb = s & 7;
      int colo = (cb ^ (r & 7)) << 3;
      int gr = (bm + r < M) ? (bm + r) : (M - 1);
      GLD_LDS16(Y + (size_t)gr * F1 + kt + colo, &As[(p * 256 + wave * 64) * 8]);
      GLD_LDS16(W2b + (size_t)r * F1 + kt + colo, &Bs[(p * 256 + wave * 64) * 8]);
    }
    __syncthreads();
#pragma unroll
    for (int k0 = 0; k0 < 64; k0 += 32) {
      int ra = wave * 16 + m15;
      bf16x8 af = *(const bf16x8*)&As[ra * 64 + ((((k0 >> 3) + q) ^ (ra & 7)) << 3)];
      bf16x8 bfr[4];
#pragma unroll
      for (int j = 0; j < 4; ++j) {
        int rb = j * 16 + m15;
        bfr[j] = *(const bf16x8*)&Bs[rb * 64 + ((((k0 >> 3) + q) ^ (rb & 7)) << 3)];
      }
#pragma unroll
      for (int j = 0; j < 4; ++j)
        acc[j] = __builtin_amdgcn_mfma_f32_16x16x32_bf16(af, bfr[j], acc[j], 0, 0, 0);
    }
    __syncthreads();
  }
  float asf[4], adf[4];
#pragma unroll
  for (int j = 0; j < 4; ++j) {
    asf[j] = a_src[j * 16 + m15];
    adf[j] = a_dst[j * 16 + m15];
  }
#pragma unroll
  for (int r = 0; r < 4; ++r) {
    int row = bm + wave * 16 + q * 4 + r;
    if (row < M) {
#pragma unroll
      for (int j = 0; j < 4; ++j) H2[(size_t)row * OUT_C + j * 16 + m15] = acc[j][r];
    }
    float s = acc[0][r] * asf[0] + acc[1][r] * asf[1] + acc[2][r] * asf[2] + acc[3][r] * asf[3];
    float d = acc[0][r] * adf[0] + acc[1][r] * adf[1] + acc[2][r] * adf[2] + acc[3][r] * adf[3];
#pragma unroll
    for (int o = 1; o < 16; o <<= 1) {
      s += __shfl_xor(s, o, 64);
      d += __shfl_xor(d, o, 64);
    }
    if (m15 == 0 && row < M) {
      as_out[row] = s;
      ad_out[row] = d;
    }
  }
}

// ---------------- CSR build ----------------
__global__ __launch_bounds__(256) void scan_block_sums(const int* __restrict__ deg,
                                                       int* __restrict__ part, int n) {
  __shared__ int sm[256];
  int t = threadIdx.x;
  int i = blockIdx.x * 256 + t;
  sm[t] = (i < n) ? deg[i] : 0;
  __syncthreads();
  for (int off = 128; off > 0; off >>= 1) {
    if (t < off) sm[t] += sm[t + off];
    __syncthreads();
  }
  if (t == 0) part[blockIdx.x] = sm[0];
}

// final scan: each block computes its own exclusive base from raw block sums
// (P <= 256 partials -> one wave-butterfly + LDS combine)
__global__ __launch_bounds__(256) void scan_final2(const int* __restrict__ deg,
                                                   const int* __restrict__ part,
                                                   int* __restrict__ row_ptr, int n) {
  __shared__ int sm[256];
  __shared__ int wsum[4];
  int t = threadIdx.x;
  int i = blockIdx.x * 256 + t;
  sm[t] = (i < n) ? deg[i] : 0;
  // exclusive base = sum of part[0..blockIdx.x-1]
  int pv = (t < blockIdx.x) ? part[t] : 0;
#pragma unroll
  for (int o = 1; o < 64; o <<= 1) pv += __shfl_xor(pv, o, 64);
  if ((t & 63) == 0) wsum[t >> 6] = pv;
  __syncthreads();
  for (int off = 1; off < 256; off <<= 1) {
    int u = (t >= off) ? sm[t - off] : 0;
    __syncthreads();
    sm[t] += u;
    __syncthreads();
  }
  int base = wsum[0] + wsum[1] + wsum[2] + wsum[3];
  if (i < n) row_ptr[i + 1] = base + sm[t];
  if (i == 0) row_ptr[0] = 0;
}

// ------- layer-1 aggregate: wave/dst, FOUR edges in flight per 32-lane half --------
// lane&31 = channel-group (8 ch, uint4), lane>>5 = edge parity; head = (lane&31)>>3.
__global__ __launch_bounds__(256) void agg1_kernel(const unsigned short* __restrict__ hb,
                                                   const float* __restrict__ as,
                                                   const float* __restrict__ ad,
                                                   const int* __restrict__ row_ptr,
                                                   const int* __restrict__ col,
                                                   const float* __restrict__ bias,
                                                   unsigned short* __restrict__ yb, int N) {
  int dst = (blockIdx.x * blockDim.x + threadIdx.x) >> 6;
  int lane = threadIdx.x & 63;
  if (dst >= N) return;
  const int s0 = row_ptr[dst], s1 = row_ptr[dst + 1];
  const int par = lane >> 5;
  const int cg = lane & 31;
  const int hh = cg >> 3;
  const float adl = ad[dst * 4 + hh];
  float acc[8];
#pragma unroll
  for (int k = 0; k < 8; ++k) acc[k] = 0.f;
  float den = 0.f;

  int i = s0 + par;
  for (; i + 6 < s1; i += 8) {  // 4 edges per parity per iter -> 8 rows in flight
    int sA = col[i], sB = col[i + 2], sC = col[i + 4], sD = col[i + 6];
    float wA = __expf(leaky(as[sA * 4 + hh] + adl));
    float wB = __expf(leaky(as[sB * 4 + hh] + adl));
    float wC = __expf(leaky(as[sC * 4 + hh] + adl));
    float wD = __expf(leaky(as[sD * 4 + hh] + adl));
    uint4 hA = *(const uint4*)(hb + (size_t)sA * F1 + cg * 8);
    uint4 hB = *(const uint4*)(hb + (size_t)sB * F1 + cg * 8);
    uint4 hC = *(const uint4*)(hb + (size_t)sC * F1 + cg * 8);
    uint4 hD = *(const uint4*)(hb + (size_t)sD * F1 + cg * 8);
    den += (wA + wB) + (wC + wD);
    const unsigned short* pa = (const unsigned short*)&hA;
    const unsigned short* pb = (const unsigned short*)&hB;
    const unsigned short* pc = (const unsigned short*)&hC;
    const unsigned short* pd = (const unsigned short*)&hD;
#pragma unroll
    for (int k = 0; k < 8; ++k) {
      acc[k] = fmaf(wA, bf2f(pa[k]), acc[k]);
      acc[k] = fmaf(wB, bf2f(pb[k]), acc[k]);
      acc[k] = fmaf(wC, bf2f(pc[k]), acc[k]);
      acc[k] = fmaf(wD, bf2f(pd[k]), acc[k]);
    }
  }
  for (; i + 2 < s1; i += 4) {  // 2 edges per parity
    int sA = col[i], sB = col[i + 2];
    float wA = __expf(leaky(as[sA * 4 + hh] + adl));
    float wB = __expf(leaky(as[sB * 4 + hh] + adl));
    uint4 hA = *(const uint4*)(hb + (size_t)sA * F1 + cg * 8);
    uint4 hB = *(const uint4*)(hb + (size_t)sB * F1 + cg * 8);
    den += wA + wB;
    const unsigned short* pa = (const unsigned short*)&hA;
    const unsigned short* pb = (const unsigned short*)&hB;
#pragma unroll
    for (int k = 0; k < 8; ++k) {
      acc[k] = fmaf(wA, bf2f(pa[k]), acc[k]);
      acc[k] = fmaf(wB, bf2f(pb[k]), acc[k]);
    }
  }
  for (; i < s1; i += 2) {
    int s = col[i];
    float w = __expf(leaky(as[s * 4 + hh] + adl));
    uint4 hv = *(const uint4*)(hb + (size_t)s * F1 + cg * 8);
    den += w;
    const unsigned short* p = (const unsigned short*)&hv;
#pragma unroll
    for (int k = 0; k < 8; ++k) acc[k] = fmaf(w, bf2f(p[k]), acc[k]);
  }
  // combine the two parities
  den += __shfl_xor(den, 32, 64);
#pragma unroll
  for (int k = 0; k < 8; ++k) acc[k] += __shfl_xor(acc[k], 32, 64);

  if (par == 0) {
    const float iv = 1.f / den;
    float4 b0 = *(const float4*)(bias + cg * 8);
    float4 b1 = *(const float4*)(bias + cg * 8 + 4);
    float bv[8] = {b0.x, b0.y, b0.z, b0.w, b1.x, b1.y, b1.z, b1.w};
    ushort4 o[2];
    unsigned short* po = (unsigned short*)o;
#pragma unroll
    for (int k = 0; k < 8; ++k) {
      float v = acc[k] * iv + bv[k];
      v = v > 0.f ? v : (__expf(v) - 1.f);
      po[k] = bf16bits(v);
    }
    *(uint4*)(yb + (size_t)dst * F1 + cg * 8) = *(uint4*)o;
  }
}

// ------- layer-2 aggregate: wave/dst, FOUR edges in flight per half ----------------
__global__ __launch_bounds__(256) void agg2_kernel(const float* __restrict__ h,
                                                   const float* __restrict__ as,
                                                   const float* __restrict__ ad,
                                                   const int* __restrict__ row_ptr,
                                                   const int* __restrict__ col,
                                                   const float* __restrict__ bias,
                                                   float* __restrict__ out, int N) {
  int dst = (blockIdx.x * blockDim.x + threadIdx.x) >> 6;
  int lane = threadIdx.x & 63;
  if (dst >= N) return;
  const int s0 = row_ptr[dst], s1 = row_ptr[dst + 1];
  const int par = lane >> 5;
  const int cg = lane & 31;
  const float adl = ad[dst];
  float a0 = 0.f, a1 = 0.f, den = 0.f;

  int i = s0 + par;
  for (; i + 6 < s1; i += 8) {
    int sA = col[i], sB = col[i + 2], sC = col[i + 4], sD = col[i + 6];
    float wA = __expf(leaky(as[sA] + adl));
    float wB = __expf(leaky(as[sB] + adl));
    float wC = __expf(leaky(as[sC] + adl));
    float wD = __expf(leaky(as[sD] + adl));
    float2 hA = *(const float2*)(h + (size_t)sA * OUT_C + cg * 2);
    float2 hB = *(const float2*)(h + (size_t)sB * OUT_C + cg * 2);
    float2 hC = *(const float2*)(h + (size_t)sC * OUT_C + cg * 2);
    float2 hD = *(const float2*)(h + (size_t)sD * OUT_C + cg * 2);
    den += (wA + wB) + (wC + wD);
    a0 = fmaf(wA, hA.x, a0); a1 = fmaf(wA, hA.y, a1);
    a0 = fmaf(wB, hB.x, a0); a1 = fmaf(wB, hB.y, a1);
    a0 = fmaf(wC, hC.x, a0); a1 = fmaf(wC, hC.y, a1);
    a0 = fmaf(wD, hD.x, a0); a1 = fmaf(wD, hD.y, a1);
  }
  for (; i + 2 < s1; i += 4) {
    int sA = col[i], sB = col[i + 2];
    float wA = __expf(leaky(as[sA] + adl));
    float wB = __expf(leaky(as[sB] + adl));
    float2 hA = *(const float2*)(h + (size_t)sA * OUT_C + cg * 2);
    float2 hB = *(const float2*)(h + (size_t)sB * OUT_C + cg * 2);
    den += wA + wB;
    a0 = fmaf(wA, hA.x, a0); a1 = fmaf(wA, hA.y, a1);
    a0 = fmaf(wB, hB.x, a0); a1 = fmaf(wB, hB.y, a1);
  }
  for (; i < s1; i += 2) {
    int s = col[i];
    float w = __expf(leaky(as[s] + adl));
    float2 hv = *(const float2*)(h + (size_t)s * OUT_C + cg * 2);
    den += w;
    a0 = fmaf(w, hv.x, a0); a1 = fmaf(w, hv.y, a1);
  }
  den += __shfl_xor(den, 32, 64);
  a0 += __shfl_xor(a0, 32, 64);
  a1 += __shfl_xor(a1, 32, 64);
  if (par == 0) {
    const float iv = 1.f / den;
    float2 bv = *(const float2*)(bias + cg * 2);
    float2 o = make_float2(a0 * iv + bv.x, a1 * iv + bv.y);
    *(float2*)(out + (size_t)dst * OUT_C + cg * 2) = o;
  }
}

extern "C" void kernel_launch(void* const* d_in, const int* in_sizes, int n_in,
                              void* d_out, int out_size, void* d_ws, size_t ws_size,
                              hipStream_t stream) {
  const float* x      = (const float*)d_in[0];
  const int*   ei     = (const int*)d_in[1];
  const float* W1     = (const float*)d_in[2];
  const float* a_src1 = (const float*)d_in[3];
  const float* a_dst1 = (const float*)d_in[4];
  const float* b1     = (const float*)d_in[5];
  const float* W2     = (const float*)d_in[6];
  const float* a_src2 = (const float*)d_in[7];
  const float* a_dst2 = (const float*)d_in[8];
  const float* b2     = (const float*)d_in[9];
  float* out = (float*)d_out;

  const int N = in_sizes[0] / IN_C;
  const int E = in_sizes[1] / 2;
  const int ET = E + N;

  char* ws = (char*)d_ws;
  size_t off = 0;
  auto alloc = [&](size_t bytes) -> void* {
    void* p = ws + off;
    off = (off + bytes + 255) & ~(size_t)255;
    return p;
  };
  unsigned short* h1b = (unsigned short*)alloc((size_t)N * F1 * 2);
  unsigned short* y1b = (unsigned short*)alloc((size_t)N * F1 * 2);
  float* h2      = (float*)alloc((size_t)N * OUT_C * 4);
  float* as1     = (float*)alloc((size_t)N * HEADS * 4);
  float* ad1     = (float*)alloc((size_t)N * HEADS * 4);
  float* as2     = (float*)alloc((size_t)N * 4);
  float* ad2     = (float*)alloc((size_t)N * 4);
  int*   deg     = (int*)alloc((size_t)N * 2 * 4);  // deg + fill, contiguous -> one memset
  int*   fill    = deg + N;
  int*   row_ptr = (int*)alloc((size_t)(N + 1) * 4);
  int*   col     = (int*)alloc((size_t)ET * 4);
  int*   part    = (int*)alloc(1024 * 4);
  unsigned short* W1b = (unsigned short*)alloc((size_t)F1 * IN_C * 2);
  unsigned short* W2b = (unsigned short*)alloc((size_t)OUT_C * F1 * 2);
  (void)off; (void)ws_size; (void)n_in; (void)out_size;

  hipMemsetAsync(deg, 0, (size_t)N * 2 * 4, stream);

  const int NBD = (ET + 255) / 256;
  const int P = (N + 255) / 256;  // scan_final2 requires P <= 256 (N <= 65536): holds for N=50000

  prep_kernel<<<NB_W1 + NB_W2 + NBD, 256, 0, stream>>>(W1, W1b, W2, W2b, ei, E, N, deg);
  scan_block_sums<<<P, 256, 0, stream>>>(deg, part, N);
  scan_final2<<<P, 256, 0, stream>>>(deg, part, row_ptr, N);

  const int NB4 = (N + 3) / 4;
  const int MB2 = ((N + 127) / 128) * 2;   // 128-row x 128-col blocks -> 782 (~3/CU)
  const int SB = (ET + 255) / 256;         // scatter trailing blocks

  // ---- layer 1 (gemm + fused scatter: independent work co-scheduled) ----
  gemm1_mfma<<<MB2 + SB, 256, 0, stream>>>(x, W1b, h1b, a_src1, a_dst1, as1, ad1, N, MB2,
                                           ei, E, N, row_ptr, fill, col);
  agg1_kernel<<<NB4, 256, 0, stream>>>(h1b, as1, ad1, row_ptr, col, b1, y1b, N);

  // ---- layer 2 ----
  gemm2_mfma<<<(N + 63) / 64, 256, 0, stream>>>(y1b, W2b, h2, a_src2, a_dst2, as2, ad2, N);
  agg2_kernel<<<NB4, 256, 0, stream>>>(h2, as2, ad2, row_ptr, col, b2, out, N);
}

// Round 6
// 499.917 us; speedup vs baseline: 1.0313x; 1.0088x over previous
//
#include <hip/hip_runtime.h>
#include <hip/hip_bf16.h>
#include <math.h>

constexpr int IN_C = 1024;
constexpr int HEADS = 4;
constexpr int F1 = 256;
constexpr int OUT_C = 64;
constexpr float NEG = 0.2f;

using bf16x8 = __attribute__((ext_vector_type(8))) short;
using f32x4 = __attribute__((ext_vector_type(4))) float;

__device__ __forceinline__ float leaky(float x) { return x > 0.f ? x : NEG * x; }

__device__ __forceinline__ unsigned short bf16bits(float v) {
  __hip_bfloat16 b = __float2bfloat16(v);
  return *reinterpret_cast<unsigned short*>(&b);
}
__device__ __forceinline__ float bf2f(unsigned short u) {
  union { unsigned u; float f; } c; c.u = (unsigned)u << 16; return c.f;
}

#define GLD_LDS16(g, l)                                                        \
  __builtin_amdgcn_global_load_lds(                                            \
      (const __attribute__((address_space(1))) void*)(g),                      \
      (__attribute__((address_space(3))) void*)(l), 16, 0, 0)

// ---------------- fused prep: cvt W1 -> bf16, cvt W2 -> bf16, degree count ----------------
constexpr int NB_W1 = (F1 * IN_C) / 256;    // 1024 (exact)
constexpr int NB_W2 = (OUT_C * F1) / 256;   // 64 (exact)

__global__ __launch_bounds__(256) void prep_kernel(const float* __restrict__ W1,
                                                   unsigned short* __restrict__ W1b,
                                                   const float* __restrict__ W2,
                                                   unsigned short* __restrict__ W2b,
                                                   const int* __restrict__ ei, int E, int N,
                                                   int* __restrict__ deg) {
  int b = blockIdx.x;
  if (b < NB_W1) {
    int i = b * 256 + threadIdx.x;
    W1b[i] = bf16bits(W1[i]);
  } else if (b < NB_W1 + NB_W2) {
    int i = (b - NB_W1) * 256 + threadIdx.x;
    W2b[i] = bf16bits(W2[i]);
  } else {
    int e = (b - NB_W1 - NB_W2) * 256 + threadIdx.x;
    if (e < E + N) {
      int dst = (e < E) ? ei[E + e] : (e - E);
      atomicAdd(&deg[dst], 1);
    }
  }
}

// ------- GEMM1: Hb[M,256] = X*W1^T (bf16 MFMA) + fused alpha dot-products ---------
// T3 minimum 2-phase pipeline + T14 split: double-buffered LDS; STAGE(t+1) issued
// BEFORE compute(t); A packed to bf16 in VGPRs and ds_written into the idle buffer
// AFTER compute issues -> the barrier waits only on loads that had a full compute
// phase to land (rounds 0-5 all drained cold-HBM A loads at every K-tile barrier:
// 126-150us at MfmaUtil 7-8% with nothing busy).
// 128-row x 128-col blocks, 512 threads (8 waves = 4 row-groups x 2 col-groups).
// LDS = 2 x (A 16KB bf16 + B 16KB) = 64KB -> 2 blocks/CU = 4 waves/SIMD.
// _rn conversion moved from read-time to stage-time: bit-identical output.
// Swizzles identical to round-5 (measured 0 bank conflicts).
__global__ __launch_bounds__(512, 4) void gemm1_mfma(const float* __restrict__ X,
                                                     const unsigned short* __restrict__ Wb,
                                                     unsigned short* __restrict__ Hb,
                                                     const float* __restrict__ a_src,
                                                     const float* __restrict__ a_dst,
                                                     float* __restrict__ as_out,
                                                     float* __restrict__ ad_out, int M, int MB2,
                                                     const int* __restrict__ ei, int E, int N,
                                                     const int* __restrict__ row_ptr,
                                                     int* __restrict__ fill,
                                                     int* __restrict__ col) {
  __shared__ unsigned short As0[128 * 64];
  __shared__ unsigned short As1[128 * 64];
  __shared__ unsigned short Bs0[128 * 64];
  __shared__ unsigned short Bs1[128 * 64];
  const int tid = threadIdx.x;

  if (blockIdx.x >= MB2) {
    // ---- fused scatter (CSR column fill) ----
    int e = (blockIdx.x - MB2) * 512 + tid;
    int ET = E + N;
    if (e < ET) {
      int src, dst;
      if (e < E) { src = ei[e]; dst = ei[E + e]; }
      else       { src = e - E; dst = e - E; }
      int pos = row_ptr[dst] + atomicAdd(&fill[dst], 1);
      col[pos] = src;
    }
    return;
  }

  const int rc = blockIdx.x >> 1;    // row-chunk (paired blocks share A rows -> L2 hit)
  const int colg = blockIdx.x & 1;   // column half
  const int wave = tid >> 6;
  const int rg = wave >> 1;          // row-group 0..3 (32 rows each)
  const int cg = wave & 1;           // col-group 0..1 (64 cols each)
  const int lane = tid & 63;
  const int m15 = lane & 15;
  const int q = lane >> 4;
  const int bm = rc * 128;

  // ---- staging indices (fixed per thread) ----
  // A: 1024 bf16-chunk slots (128 rows x 8 chunks of 8 K-elems); 2 per thread.
  const int sA0 = tid, sA1 = 512 + tid;
  const int rA0 = sA0 >> 3, cA0 = sA0 & 7;
  const int rA1 = sA1 >> 3, cA1 = sA1 & 7;
  const int grA0 = (bm + rA0 < M) ? (bm + rA0) : (M - 1);
  const int grA1 = (bm + rA1 < M) ? (bm + rA1) : (M - 1);
  const float* aSrc0 = X + (size_t)grA0 * IN_C + ((cA0 ^ (rA0 & 7)) << 3);
  const float* aSrc1 = X + (size_t)grA1 * IN_C + ((cA1 ^ (rA1 & 7)) << 3);
  // B: 1024 16B slots; 2 per thread (GLD_LDS: wave-uniform base + lane*16).
  const int rB0 = sA0 >> 3, cB0 = sA0 & 7;
  const int rB1 = sA1 >> 3, cB1 = sA1 & 7;
  const unsigned short* bSrc0 = Wb + (size_t)(colg * 128 + rB0) * IN_C + ((cB0 ^ (rB0 & 7)) << 3);
  const unsigned short* bSrc1 = Wb + (size_t)(colg * 128 + rB1) * IN_C + ((cB1 ^ (rB1 & 7)) << 3);

  f32x4 acc[2][4];
#pragma unroll
  for (int i = 0; i < 2; ++i)
#pragma unroll
    for (int j = 0; j < 4; ++j) acc[i][j] = (f32x4){0.f, 0.f, 0.f, 0.f};

  float4 f00, f01, f10, f11;   // in-flight A registers (2 chunks x 32B)

#define A_LOAD(KT)                                                             \
  f00 = *(const float4*)(aSrc0 + (KT));                                        \
  f01 = *(const float4*)(aSrc0 + (KT) + 4);                                    \
  f10 = *(const float4*)(aSrc1 + (KT));                                        \
  f11 = *(const float4*)(aSrc1 + (KT) + 4);

#define B_STAGE(KT, BS)                                                        \
  GLD_LDS16(bSrc0 + (KT), &BS[sA0 * 8]);                                       \
  GLD_LDS16(bSrc1 + (KT), &BS[sA1 * 8]);

#define A_WRITE(AS)                                                            \
  {                                                                            \
    union { uint4 u; __hip_bfloat162 h[4]; } pk;                               \
    pk.h[0] = __float22bfloat162_rn(make_float2(f00.x, f00.y));                \
    pk.h[1] = __float22bfloat162_rn(make_float2(f00.z, f00.w));                \
    pk.h[2] = __float22bfloat162_rn(make_float2(f01.x, f01.y));                \
    pk.h[3] = __float22bfloat162_rn(make_float2(f01.z, f01.w));                \
    *(uint4*)&AS[sA0 * 8] = pk.u;                                              \
    pk.h[0] = __float22bfloat162_rn(make_float2(f10.x, f10.y));                \
    pk.h[1] = __float22bfloat162_rn(make_float2(f10.z, f10.w));                \
    pk.h[2] = __float22bfloat162_rn(make_float2(f11.x, f11.y));                \
    pk.h[3] = __float22bfloat162_rn(make_float2(f11.z, f11.w));                \
    *(uint4*)&AS[sA1 * 8] = pk.u;                                              \
  }

#define COMPUTE(AS, BS)                                                        \
  {                                                                            \
    _Pragma("unroll")                                                          \
    for (int k0 = 0; k0 < 64; k0 += 32) {                                      \
      bf16x8 af[2], bfr[4];                                                    \
      _Pragma("unroll")                                                        \
      for (int i = 0; i < 2; ++i) {                                            \
        int ra = rg * 32 + i * 16 + m15;                                       \
        af[i] = *(const bf16x8*)&AS[ra * 64 + ((((k0 >> 3) + q) ^ (ra & 7)) << 3)]; \
      }                                                                        \
      _Pragma("unroll")                                                        \
      for (int j = 0; j < 4; ++j) {                                            \
        int rb = cg * 64 + j * 16 + m15;                                       \
        bfr[j] = *(const bf16x8*)&BS[rb * 64 + ((((k0 >> 3) + q) ^ (rb & 7)) << 3)]; \
      }                                                                        \
      _Pragma("unroll")                                                        \
      for (int i = 0; i < 2; ++i)                                              \
        _Pragma("unroll")                                                      \
        for (int j = 0; j < 4; ++j)                                            \
          acc[i][j] = __builtin_amdgcn_mfma_f32_16x16x32_bf16(af[i], bfr[j], acc[i][j], 0, 0, 0); \
    }                                                                          \
  }

  // ---- prologue: stage tile kt=0 into buf 0 ----
  A_LOAD(0);
  B_STAGE(0, Bs0);
  A_WRITE(As0);
  __syncthreads();

  // ---- main loop: 2 tiles per iteration, compile-time buffer indices ----
  for (int kt = 0; kt < IN_C; kt += 128) {
    // tile kt (buf0); prefetch kt+64 into buf1 (kt+64 <= 960 < IN_C always)
    A_LOAD(kt + 64);
    B_STAGE(kt + 64, Bs1);
    COMPUTE(As0, Bs0);
    A_WRITE(As1);
    __syncthreads();
    // tile kt+64 (buf1); prefetch kt+128 into buf0 unless last
    if (kt + 128 < IN_C) {
      A_LOAD(kt + 128);
      B_STAGE(kt + 128, Bs0);
    }
    COMPUTE(As1, Bs1);
    if (kt + 128 < IN_C) { A_WRITE(As0); }
    __syncthreads();
  }
#undef A_LOAD
#undef B_STAGE
#undef A_WRITE
#undef COMPUTE

  const int cbase = colg * 128 + cg * 64;   // this wave's 64-col slice
  const int head = colg * 2 + cg;
  float asf[4], adf[4];
#pragma unroll
  for (int j = 0; j < 4; ++j) {
    asf[j] = a_src[cbase + j * 16 + m15];
    adf[j] = a_dst[cbase + j * 16 + m15];
  }
#pragma unroll
  for (int i = 0; i < 2; ++i) {
#pragma unroll
    for (int r = 0; r < 4; ++r) {
      int row = bm + rg * 32 + i * 16 + q * 4 + r;
      if (row < M) {
#pragma unroll
        for (int j = 0; j < 4; ++j)
          Hb[(size_t)row * F1 + cbase + j * 16 + m15] = bf16bits(acc[i][j][r]);
      }
      float s = acc[i][0][r] * asf[0] + acc[i][1][r] * asf[1] +
                acc[i][2][r] * asf[2] + acc[i][3][r] * asf[3];
      float d = acc[i][0][r] * adf[0] + acc[i][1][r] * adf[1] +
                acc[i][2][r] * adf[2] + acc[i][3][r] * adf[3];
#pragma unroll
      for (int o = 1; o < 16; o <<= 1) {
        s += __shfl_xor(s, o, 64);
        d += __shfl_xor(d, o, 64);
      }
      if (m15 == 0 && row < M) {
        as_out[row * HEADS + head] = s;
        ad_out[row * HEADS + head] = d;
      }
    }
  }
}

// ------- GEMM2: H2[M,64] = Y(bf16)*W2^T (bf16 MFMA) + fused alpha -----------------
__global__ __launch_bounds__(256, 4) void gemm2_mfma(const unsigned short* __restrict__ Y,
                                                     const unsigned short* __restrict__ W2b,
                                                     float* __restrict__ H2,
                                                     const float* __restrict__ a_src,
                                                     const float* __restrict__ a_dst,
                                                     float* __restrict__ as_out,
                                                     float* __restrict__ ad_out, int M) {
  __shared__ unsigned short As[64 * 64];
  __shared__ unsigned short Bs[64 * 64];
  const int tid = threadIdx.x;
  const int wave = tid >> 6;
  const int lane = tid & 63;
  const int m15 = lane & 15;
  const int q = lane >> 4;
  const int bm = blockIdx.x * 64;

  f32x4 acc[4];
#pragma unroll
  for (int j = 0; j < 4; ++j) acc[j] = (f32x4){0.f, 0.f, 0.f, 0.f};

  for (int kt = 0; kt < F1; kt += 64) {
#pragma unroll
    for (int p = 0; p < 2; ++p) {
      int s = p * 256 + tid;
      int r = s >> 3;
      int cb = s & 7;
      int colo = (cb ^ (r & 7)) << 3;
      int gr = (bm + r < M) ? (bm + r) : (M - 1);
      GLD_LDS16(Y + (size_t)gr * F1 + kt + colo, &As[(p * 256 + wave * 64) * 8]);
      GLD_LDS16(W2b + (size_t)r * F1 + kt + colo, &Bs[(p * 256 + wave * 64) * 8]);
    }
    __syncthreads();
#pragma unroll
    for (int k0 = 0; k0 < 64; k0 += 32) {
      int ra = wave * 16 + m15;
      bf16x8 af = *(const bf16x8*)&As[ra * 64 + ((((k0 >> 3) + q) ^ (ra & 7)) << 3)];
      bf16x8 bfr[4];
#pragma unroll
      for (int j = 0; j < 4; ++j) {
        int rb = j * 16 + m15;
        bfr[j] = *(const bf16x8*)&Bs[rb * 64 + ((((k0 >> 3) + q) ^ (rb & 7)) << 3)];
      }
#pragma unroll
      for (int j = 0; j < 4; ++j)
        acc[j] = __builtin_amdgcn_mfma_f32_16x16x32_bf16(af, bfr[j], acc[j], 0, 0, 0);
    }
    __syncthreads();
  }
  float asf[4], adf[4];
#pragma unroll
  for (int j = 0; j < 4; ++j) {
    asf[j] = a_src[j * 16 + m15];
    adf[j] = a_dst[j * 16 + m15];
  }
#pragma unroll
  for (int r = 0; r < 4; ++r) {
    int row = bm + wave * 16 + q * 4 + r;
    if (row < M) {
#pragma unroll
      for (int j = 0; j < 4; ++j) H2[(size_t)row * OUT_C + j * 16 + m15] = acc[j][r];
    }
    float s = acc[0][r] * asf[0] + acc[1][r] * asf[1] + acc[2][r] * asf[2] + acc[3][r] * asf[3];
    float d = acc[0][r] * adf[0] + acc[1][r] * adf[1] + acc[2][r] * adf[2] + acc[3][r] * adf[3];
#pragma unroll
    for (int o = 1; o < 16; o <<= 1) {
      s += __shfl_xor(s, o, 64);
      d += __shfl_xor(d, o, 64);
    }
    if (m15 == 0 && row < M) {
      as_out[row] = s;
      ad_out[row] = d;
    }
  }
}

// ---------------- CSR build ----------------
__global__ __launch_bounds__(256) void scan_block_sums(const int* __restrict__ deg,
                                                       int* __restrict__ part, int n) {
  __shared__ int sm[256];
  int t = threadIdx.x;
  int i = blockIdx.x * 256 + t;
  sm[t] = (i < n) ? deg[i] : 0;
  __syncthreads();
  for (int off = 128; off > 0; off >>= 1) {
    if (t < off) sm[t] += sm[t + off];
    __syncthreads();
  }
  if (t == 0) part[blockIdx.x] = sm[0];
}

__global__ __launch_bounds__(256) void scan_final2(const int* __restrict__ deg,
                                                   const int* __restrict__ part,
                                                   int* __restrict__ row_ptr, int n) {
  __shared__ int sm[256];
  __shared__ int wsum[4];
  int t = threadIdx.x;
  int i = blockIdx.x * 256 + t;
  sm[t] = (i < n) ? deg[i] : 0;
  int pv = (t < blockIdx.x) ? part[t] : 0;
#pragma unroll
  for (int o = 1; o < 64; o <<= 1) pv += __shfl_xor(pv, o, 64);
  if ((t & 63) == 0) wsum[t >> 6] = pv;
  __syncthreads();
  for (int off = 1; off < 256; off <<= 1) {
    int u = (t >= off) ? sm[t - off] : 0;
    __syncthreads();
    sm[t] += u;
    __syncthreads();
  }
  int base = wsum[0] + wsum[1] + wsum[2] + wsum[3];
  if (i < n) row_ptr[i + 1] = base + sm[t];
  if (i == 0) row_ptr[0] = 0;
}

// ------- layer-1 aggregate: wave/dst, FOUR edges in flight per 32-lane half --------
__global__ __launch_bounds__(256) void agg1_kernel(const unsigned short* __restrict__ hb,
                                                   const float* __restrict__ as,
                                                   const float* __restrict__ ad,
                                                   const int* __restrict__ row_ptr,
                                                   const int* __restrict__ col,
                                                   const float* __restrict__ bias,
                                                   unsigned short* __restrict__ yb, int N) {
  int dst = (blockIdx.x * blockDim.x + threadIdx.x) >> 6;
  int lane = threadIdx.x & 63;
  if (dst >= N) return;
  const int s0 = row_ptr[dst], s1 = row_ptr[dst + 1];
  const int par = lane >> 5;
  const int cg = lane & 31;
  const int hh = cg >> 3;
  const float adl = ad[dst * 4 + hh];
  float acc[8];
#pragma unroll
  for (int k = 0; k < 8; ++k) acc[k] = 0.f;
  float den = 0.f;

  int i = s0 + par;
  for (; i + 6 < s1; i += 8) {
    int sA = col[i], sB = col[i + 2], sC = col[i + 4], sD = col[i + 6];
    float wA = __expf(leaky(as[sA * 4 + hh] + adl));
    float wB = __expf(leaky(as[sB * 4 + hh] + adl));
    float wC = __expf(leaky(as[sC * 4 + hh] + adl));
    float wD = __expf(leaky(as[sD * 4 + hh] + adl));
    uint4 hA = *(const uint4*)(hb + (size_t)sA * F1 + cg * 8);
    uint4 hB = *(const uint4*)(hb + (size_t)sB * F1 + cg * 8);
    uint4 hC = *(const uint4*)(hb + (size_t)sC * F1 + cg * 8);
    uint4 hD = *(const uint4*)(hb + (size_t)sD * F1 + cg * 8);
    den += (wA + wB) + (wC + wD);
    const unsigned short* pa = (const unsigned short*)&hA;
    const unsigned short* pb = (const unsigned short*)&hB;
    const unsigned short* pc = (const unsigned short*)&hC;
    const unsigned short* pd = (const unsigned short*)&hD;
#pragma unroll
    for (int k = 0; k < 8; ++k) {
      acc[k] = fmaf(wA, bf2f(pa[k]), acc[k]);
      acc[k] = fmaf(wB, bf2f(pb[k]), acc[k]);
      acc[k] = fmaf(wC, bf2f(pc[k]), acc[k]);
      acc[k] = fmaf(wD, bf2f(pd[k]), acc[k]);
    }
  }
  for (; i + 2 < s1; i += 4) {
    int sA = col[i], sB = col[i + 2];
    float wA = __expf(leaky(as[sA * 4 + hh] + adl));
    float wB = __expf(leaky(as[sB * 4 + hh] + adl));
    uint4 hA = *(const uint4*)(hb + (size_t)sA * F1 + cg * 8);
    uint4 hB = *(const uint4*)(hb + (size_t)sB * F1 + cg * 8);
    den += wA + wB;
    const unsigned short* pa = (const unsigned short*)&hA;
    const unsigned short* pb = (const unsigned short*)&hB;
#pragma unroll
    for (int k = 0; k < 8; ++k) {
      acc[k] = fmaf(wA, bf2f(pa[k]), acc[k]);
      acc[k] = fmaf(wB, bf2f(pb[k]), acc[k]);
    }
  }
  for (; i < s1; i += 2) {
    int s = col[i];
    float w = __expf(leaky(as[s * 4 + hh] + adl));
    uint4 hv = *(const uint4*)(hb + (size_t)s * F1 + cg * 8);
    den += w;
    const unsigned short* p = (const unsigned short*)&hv;
#pragma unroll
    for (int k = 0; k < 8; ++k) acc[k] = fmaf(w, bf2f(p[k]), acc[k]);
  }
  den += __shfl_xor(den, 32, 64);
#pragma unroll
  for (int k = 0; k < 8; ++k) acc[k] += __shfl_xor(acc[k], 32, 64);

  if (par == 0) {
    const float iv = 1.f / den;
    float4 b0 = *(const float4*)(bias + cg * 8);
    float4 b1 = *(const float4*)(bias + cg * 8 + 4);
    float bv[8] = {b0.x, b0.y, b0.z, b0.w, b1.x, b1.y, b1.z, b1.w};
    ushort4 o[2];
    unsigned short* po = (unsigned short*)o;
#pragma unroll
    for (int k = 0; k < 8; ++k) {
      float v = acc[k] * iv + bv[k];
      v = v > 0.f ? v : (__expf(v) - 1.f);
      po[k] = bf16bits(v);
    }
    *(uint4*)(yb + (size_t)dst * F1 + cg * 8) = *(uint4*)o;
  }
}

// ------- layer-2 aggregate: wave/dst, FOUR edges in flight per half ----------------
__global__ __launch_bounds__(256) void agg2_kernel(const float* __restrict__ h,
                                                   const float* __restrict__ as,
                                                   const float* __restrict__ ad,
                                                   const int* __restrict__ row_ptr,
                                                   const int* __restrict__ col,
                                                   const float* __restrict__ bias,
                                                   float* __restrict__ out, int N) {
  int dst = (blockIdx.x * blockDim.x + threadIdx.x) >> 6;
  int lane = threadIdx.x & 63;
  if (dst >= N) return;
  const int s0 = row_ptr[dst], s1 = row_ptr[dst + 1];
  const int par = lane >> 5;
  const int cg = lane & 31;
  const float adl = ad[dst];
  float a0 = 0.f, a1 = 0.f, den = 0.f;

  int i = s0 + par;
  for (; i + 6 < s1; i += 8) {
    int sA = col[i], sB = col[i + 2], sC = col[i + 4], sD = col[i + 6];
    float wA = __expf(leaky(as[sA] + adl));
    float wB = __expf(leaky(as[sB] + adl));
    float wC = __expf(leaky(as[sC] + adl));
    float wD = __expf(leaky(as[sD] + adl));
    float2 hA = *(const float2*)(h + (size_t)sA * OUT_C + cg * 2);
    float2 hB = *(const float2*)(h + (size_t)sB * OUT_C + cg * 2);
    float2 hC = *(const float2*)(h + (size_t)sC * OUT_C + cg * 2);
    float2 hD = *(const float2*)(h + (size_t)sD * OUT_C + cg * 2);
    den += (wA + wB) + (wC + wD);
    a0 = fmaf(wA, hA.x, a0); a1 = fmaf(wA, hA.y, a1);
    a0 = fmaf(wB, hB.x, a0); a1 = fmaf(wB, hB.y, a1);
    a0 = fmaf(wC, hC.x, a0); a1 = fmaf(wC, hC.y, a1);
    a0 = fmaf(wD, hD.x, a0); a1 = fmaf(wD, hD.y, a1);
  }
  for (; i + 2 < s1; i += 4) {
    int sA = col[i], sB = col[i + 2];
    float wA = __expf(leaky(as[sA] + adl));
    float wB = __expf(leaky(as[sB] + adl));
    float2 hA = *(const float2*)(h + (size_t)sA * OUT_C + cg * 2);
    float2 hB = *(const float2*)(h + (size_t)sB * OUT_C + cg * 2);
    den += wA + wB;
    a0 = fmaf(wA, hA.x, a0); a1 = fmaf(wA, hA.y, a1);
    a0 = fmaf(wB, hB.x, a0); a1 = fmaf(wB, hB.y, a1);
  }
  for (; i < s1; i += 2) {
    int s = col[i];
    float w = __expf(leaky(as[s] + adl));
    float2 hv = *(const float2*)(h + (size_t)s * OUT_C + cg * 2);
    den += w;
    a0 = fmaf(w, hv.x, a0); a1 = fmaf(w, hv.y, a1);
  }
  den += __shfl_xor(den, 32, 64);
  a0 += __shfl_xor(a0, 32, 64);
  a1 += __shfl_xor(a1, 32, 64);
  if (par == 0) {
    const float iv = 1.f / den;
    float2 bv = *(const float2*)(bias + cg * 2);
    float2 o = make_float2(a0 * iv + bv.x, a1 * iv + bv.y);
    *(float2*)(out + (size_t)dst * OUT_C + cg * 2) = o;
  }
}

extern "C" void kernel_launch(void* const* d_in, const int* in_sizes, int n_in,
                              void* d_out, int out_size, void* d_ws, size_t ws_size,
                              hipStream_t stream) {
  const float* x      = (const float*)d_in[0];
  const int*   ei     = (const int*)d_in[1];
  const float* W1     = (const float*)d_in[2];
  const float* a_src1 = (const float*)d_in[3];
  const float* a_dst1 = (const float*)d_in[4];
  const float* b1     = (const float*)d_in[5];
  const float* W2     = (const float*)d_in[6];
  const float* a_src2 = (const float*)d_in[7];
  const float* a_dst2 = (const float*)d_in[8];
  const float* b2     = (const float*)d_in[9];
  float* out = (float*)d_out;

  const int N = in_sizes[0] / IN_C;
  const int E = in_sizes[1] / 2;
  const int ET = E + N;

  char* ws = (char*)d_ws;
  size_t off = 0;
  auto alloc = [&](size_t bytes) -> void* {
    void* p = ws + off;
    off = (off + bytes + 255) & ~(size_t)255;
    return p;
  };
  unsigned short* h1b = (unsigned short*)alloc((size_t)N * F1 * 2);
  unsigned short* y1b = (unsigned short*)alloc((size_t)N * F1 * 2);
  float* h2      = (float*)alloc((size_t)N * OUT_C * 4);
  float* as1     = (float*)alloc((size_t)N * HEADS * 4);
  float* ad1     = (float*)alloc((size_t)N * HEADS * 4);
  float* as2     = (float*)alloc((size_t)N * 4);
  float* ad2     = (float*)alloc((size_t)N * 4);
  int*   deg     = (int*)alloc((size_t)N * 2 * 4);  // deg + fill, contiguous -> one memset
  int*   fill    = deg + N;
  int*   row_ptr = (int*)alloc((size_t)(N + 1) * 4);
  int*   col     = (int*)alloc((size_t)ET * 4);
  int*   part    = (int*)alloc(1024 * 4);
  unsigned short* W1b = (unsigned short*)alloc((size_t)F1 * IN_C * 2);
  unsigned short* W2b = (unsigned short*)alloc((size_t)OUT_C * F1 * 2);
  (void)off; (void)ws_size; (void)n_in; (void)out_size;

  hipMemsetAsync(deg, 0, (size_t)N * 2 * 4, stream);

  const int NBD = (ET + 255) / 256;
  const int P = (N + 255) / 256;  // scan_final2 requires P <= 256 (N <= 65536): holds for N=50000

  prep_kernel<<<NB_W1 + NB_W2 + NBD, 256, 0, stream>>>(W1, W1b, W2, W2b, ei, E, N, deg);
  scan_block_sums<<<P, 256, 0, stream>>>(deg, part, N);
  scan_final2<<<P, 256, 0, stream>>>(deg, part, row_ptr, N);

  const int NB4 = (N + 3) / 4;
  const int MB2 = ((N + 127) / 128) * 2;   // 128-row x 128-col blocks -> 782
  const int SB = (ET + 511) / 512;         // scatter trailing blocks (512 thr)

  // ---- layer 1 (gemm + fused scatter: independent work co-scheduled) ----
  gemm1_mfma<<<MB2 + SB, 512, 0, stream>>>(x, W1b, h1b, a_src1, a_dst1, as1, ad1, N, MB2,
                                           ei, E, N, row_ptr, fill, col);
  agg1_kernel<<<NB4, 256, 0, stream>>>(h1b, as1, ad1, row_ptr, col, b1, y1b, N);

  // ---- layer 2 ----
  gemm2_mfma<<<(N + 63) / 64, 256, 0, stream>>>(y1b, W2b, h2, a_src2, a_dst2, as2, ad2, N);
  agg2_kernel<<<NB4, 256, 0, stream>>>(h2, as2, ad2, row_ptr, col, b2, out, N);
}